// Round 14
// baseline (144.418 us; speedup 1.0000x reference)
//
#include <hip/hip_runtime.h>
#include <hip/hip_bf16.h>

// out[b,h,w,dy*9+dx] = leaky_relu( mean_c( prv[b,h,w,c] * nxt[b,h+dy-4,w+dx-4,c] ), 0.1 )
// R14: load-pipe duty-cycle maximization on the verified 16x16 banded-MFMA core.
//  - A (prv) never leaves registers: each wave's row is private; direct per-wave
//    frag loads streamed one k-sub ahead (removes 30% of barrier-coupled bytes).
//  - B (nxt): LDS double-buffer (74 KB), TWO k-steps of register prefetch always in
//    flight (phases fully unrolled; xb parity pair -> all-static indexing, rule #20).
//  - one non-draining barrier per phase (lgkmcnt only); per-block k-stagger.

#define B_ 8
#define H_ 128
#define W_ 128
#define C_ 192
#define ND 9
#define NDISP 81
#define HT 16           // tile rows
#define WT 16           // tile cols
#define KS 32           // channels per k-step
#define NK 6            // 192/32
#define BROWS 24        // HT+8 staged nxt rows
#define BCOLS 24        // WT+8 staged nxt cols
#define BPIX (BROWS * BCOLS)   // 576
#define BSTR 577               // odd 8B-slot stride (granule-major)
#define BSLOTS (8 * BSTR)      // 4616
#define NSB 5                  // B granule-slots per thread; slot 4 covers tid<512

typedef short short8 __attribute__((ext_vector_type(8)));
typedef short short4_t __attribute__((ext_vector_type(4)));
typedef float f32x4 __attribute__((ext_vector_type(4)));

static __device__ __forceinline__ short bf1(float f) {
    __hip_bfloat16 h = __float2bfloat16(f);   // pairs fuse to v_cvt_pk_bf16_f32
    return __builtin_bit_cast(short, h);
}

static __device__ __forceinline__ short4_t cvt4(float4 v) {
    short4_t r;
    r[0] = bf1(v.x); r[1] = bf1(v.y); r[2] = bf1(v.z); r[3] = bf1(v.w);
    return r;
}

static __device__ __forceinline__ short8 cat(short4_t u, short4_t v) {
    return __builtin_shufflevector(u, v, 0, 1, 2, 3, 4, 5, 6, 7);
}

static __device__ __forceinline__ int mod6(int v) {   // v in [0, 12]
    v -= (v >= 6) ? 6 : 0;
    v -= (v >= 6) ? 6 : 0;
    return v;
}

// LDS-fence + barrier WITHOUT vmcnt drain: outstanding global loads stay in flight.
static __device__ __forceinline__ void barrier_no_vm_drain() {
    asm volatile("s_waitcnt lgkmcnt(0)\n\ts_barrier" ::: "memory");
}

__global__ __launch_bounds__(1024, 4)
void cv_mfma(const float* __restrict__ prv, const float* __restrict__ nxt,
             float* __restrict__ out) {
    __shared__ short4_t sm[2][BSLOTS];   // 2 x 36.9 KB (B only)

    const int tid = threadIdx.x;
    const int w0 = blockIdx.x * WT;
    const int h0 = blockIdx.y * HT;
    const int b  = blockIdx.z;

    const int lane = tid & 63;
    const int wid  = tid >> 6;      // 0..15: wave owns output row h0+wid
    const int lq = lane & 15;
    const int lc = lane >> 4;

    const int tp = tid >> 3;        // 0..127: B pixel sub-index for staging
    const int c8 = tid & 7;         // 0..7: 4-channel granule within k-step

    // ---- B staging offsets (k-step adds ks*KS)
    int boff[NSB];
    unsigned bmask = 0;
#pragma unroll
    for (int i = 0; i < NSB; ++i) {
        const int p = tp + 128 * i;        // 0..639; slot 4 valid only p<576
        const int row = p / BCOLS;
        const int col = p - row * BCOLS;
        const int gh = h0 - 4 + row;
        const int gw = w0 - 4 + col;
        const bool inb = (p < BPIX) && ((unsigned)gh < (unsigned)H_) && ((unsigned)gw < (unsigned)W_);
        if (inb) bmask |= (1u << i);
        boff[i] = ((b * H_ + (inb ? gh : 0)) * W_ + (inb ? gw : 0)) * C_ + c8 * 4;
    }
    const bool wr4 = (tid < 512);   // slot-4 write coverage, wave-uniform

    // ---- A: direct per-wave frag address (this thread reads pixel (wid, lq), ch 8*lc)
    const int aoff = ((b * H_ + h0 + wid) * W_ + w0 + lq) * C_ + lc * 8;

    // ---- per-block k-phase stagger (decorrelate chip-wide load bursts)
    const int start = mod6((int)(blockIdx.x + blockIdx.y + blockIdx.z) % 12);

    // ---- prologue: A(k0) + B(k0) + B(k1) in flight
    float4 xa0, xa1;
    float4 xb0[NSB], xb1[NSB];
    {
        const int c0 = start * KS;
        xa0 = *(const float4*)(prv + aoff + c0);
        xa1 = *(const float4*)(prv + aoff + c0 + 4);
#pragma unroll
        for (int i = 0; i < NSB; ++i) {
            xb0[i] = make_float4(0.f, 0.f, 0.f, 0.f);
            if (bmask & (1u << i)) xb0[i] = *(const float4*)(nxt + boff[i] + c0);
        }
        const int c1 = mod6(start + 1) * KS;
#pragma unroll
        for (int i = 0; i < NSB; ++i) {
            xb1[i] = make_float4(0.f, 0.f, 0.f, 0.f);
            if (bmask & (1u << i)) xb1[i] = *(const float4*)(nxt + boff[i] + c1);
        }
    }

    f32x4 acc[ND][2];
#pragma unroll
    for (int d = 0; d < ND; ++d) {
        acc[d][0] = (f32x4){0.f, 0.f, 0.f, 0.f};
        acc[d][1] = (f32x4){0.f, 0.f, 0.f, 0.f};
    }

    // ---- phases, fully unrolled; XB parity array is both write-source (k) and
    // reload-dest (k+2). Single non-draining barrier per phase (R13-verified safe).
#define PHASE(IT, XB)                                                              \
    {                                                                              \
        short4_t* sB = sm[IT & 1];                                                 \
        /* write B(IT): vmcnt waits only these 2-phase-old loads */                \
        _Pragma("unroll")                                                          \
        for (int i = 0; i < NSB - 1; ++i)                                          \
            sB[c8 * BSTR + tp + 128 * i] = cvt4(XB[i]);                            \
        if (wr4) sB[c8 * BSTR + tp + 512] = cvt4(XB[NSB - 1]);                     \
        /* A frag for this phase (loaded last phase / prologue) */                 \
        const short8 afrag = cat(cvt4(xa0), cvt4(xa1));                            \
        if (IT + 1 < NK) { /* issue A(IT+1) */                                     \
            const int cn = mod6(start + IT + 1) * KS;                              \
            xa0 = *(const float4*)(prv + aoff + cn);                               \
            xa1 = *(const float4*)(prv + aoff + cn + 4);                           \
        }                                                                          \
        if (IT + 2 < NK) { /* issue B(IT+2); stays in flight 2 phases */           \
            const int cb = mod6(start + IT + 2) * KS;                              \
            _Pragma("unroll")                                                      \
            for (int i = 0; i < NSB; ++i) {                                        \
                if (bmask & (1u << i)) XB[i] = *(const float4*)(nxt + boff[i] + cb); \
            }                                                                      \
        }                                                                          \
        barrier_no_vm_drain();                                                     \
        _Pragma("unroll")                                                          \
        for (int dy = 0; dy < ND; ++dy) {                                          \
            const int pB = (wid + dy) * BCOLS + lq;                                \
            const short8 b0v = cat(sB[2 * lc * BSTR + pB], sB[(2 * lc + 1) * BSTR + pB]); \
            const short8 b1v = cat(sB[2 * lc * BSTR + pB + 8], sB[(2 * lc + 1) * BSTR + pB + 8]); \
            acc[dy][0] = __builtin_amdgcn_mfma_f32_16x16x32_bf16(afrag, b0v, acc[dy][0], 0, 0, 0); \
            acc[dy][1] = __builtin_amdgcn_mfma_f32_16x16x32_bf16(afrag, b1v, acc[dy][1], 0, 0, 0); \
        }                                                                          \
    }

    PHASE(0, xb0)
    PHASE(1, xb1)
    PHASE(2, xb0)
    PHASE(3, xb1)
    PHASE(4, xb0)
    PHASE(5, xb1)
#undef PHASE

    // ---- epilogue (R5/R12/R13-verified): D col=lane&15 (q), D row=4*lc+rg (rD=w-pos).
    // rows rD<8 from tile0 (dx=q-rD), rD>=8 from tile1 (dx=q-rD+8); exclusive+complete.
    const float inv = 1.0f / (float)C_;
    const int h = h0 + wid;
    if (lc < 2) {
#pragma unroll
        for (int rg = 0; rg < 4; ++rg) {
            const int r = 4 * lc + rg;
            const int dx = lq - r;
            if (dx >= 0 && dx <= 8) {
                float* o = out + (size_t)((b * H_ + h) * W_ + w0 + r) * NDISP + dx;
#pragma unroll
                for (int dy = 0; dy < ND; ++dy) {
                    const float v = acc[dy][0][rg] * inv;
                    o[dy * ND] = v >= 0.f ? v : 0.1f * v;
                }
            }
        }
    } else {
#pragma unroll
        for (int rg = 0; rg < 4; ++rg) {
            const int r = 4 * lc + rg;       // 8..15
            const int dx = lq - r + 8;
            if (dx >= 0 && dx <= 8) {
                float* o = out + (size_t)((b * H_ + h) * W_ + w0 + r) * NDISP + dx;
#pragma unroll
                for (int dy = 0; dy < ND; ++dy) {
                    const float v = acc[dy][1][rg] * inv;
                    o[dy * ND] = v >= 0.f ? v : 0.1f * v;
                }
            }
        }
    }
}

extern "C" void kernel_launch(void* const* d_in, const int* in_sizes, int n_in,
                              void* d_out, int out_size, void* d_ws, size_t ws_size,
                              hipStream_t stream) {
    const float* prv = (const float*)d_in[0];
    const float* nxt = (const float*)d_in[1];
    float* out = (float*)d_out;

    dim3 grid(W_ / WT, H_ / HT, B_);   // (8, 8, 8) = 512 blocks x 1024 threads
    cv_mfma<<<grid, 1024, 0, stream>>>(prv, nxt, out);
}

// Round 15
// 75.220 us; speedup vs baseline: 1.9199x; 1.9199x over previous
//
#include <hip/hip_runtime.h>
#include <hip/hip_bf16.h>

// out[b,h,w,dy*9+dx] = leaky_relu( mean_c( prv[b,h,w,c] * nxt[b,h+dy-4,w+dx-4,c] ), 0.1 )
// R15: 16x16 tile, KS=64 (256B DRAM runs), A in registers (wave-private row),
// B-only LDS double-buffer (2x73.9KB). Per phase: compute(it) interleaved with
// load+LDS-write of B(it+1) into the other buffer (free by barrier-interval proof:
// the end-of-phase barrier guarantees all waves finished compute(it-1), which was
// the last reader of that buffer). One lgkm-only barrier per phase. No stagger.

#define B_ 8
#define H_ 128
#define W_ 128
#define C_ 192
#define ND 9
#define NDISP 81
#define HT 16           // tile rows
#define WT 16           // tile cols
#define KS 64           // channels per phase
#define NK 3            // 192/64
#define BROWS 24        // HT+8 staged nxt rows
#define BCOLS 24        // WT+8 staged nxt cols
#define BPIX (BROWS * BCOLS)   // 576
#define BSTR 577               // odd 8B-slot stride (granule-major)
#define BSLOTS (16 * BSTR)     // 9232 slots = 73.9 KB per buffer
#define NSB 9                  // B granule-slots per thread (576*16/1024), exact
#define NB1 5                  // batch 1 slots
#define NB2 4                  // batch 2 slots

typedef short short8 __attribute__((ext_vector_type(8)));
typedef short short4_t __attribute__((ext_vector_type(4)));
typedef float f32x4 __attribute__((ext_vector_type(4)));

static __device__ __forceinline__ short bf1(float f) {
    __hip_bfloat16 h = __float2bfloat16(f);   // pairs fuse to v_cvt_pk_bf16_f32
    return __builtin_bit_cast(short, h);
}

static __device__ __forceinline__ short4_t cvt4(float4 v) {
    short4_t r;
    r[0] = bf1(v.x); r[1] = bf1(v.y); r[2] = bf1(v.z); r[3] = bf1(v.w);
    return r;
}

static __device__ __forceinline__ short8 cat(short4_t u, short4_t v) {
    return __builtin_shufflevector(u, v, 0, 1, 2, 3, 4, 5, 6, 7);
}

// LDS-fence + barrier WITHOUT vmcnt drain: outstanding global loads stay in flight.
static __device__ __forceinline__ void barrier_lgkm() {
    asm volatile("s_waitcnt lgkmcnt(0)\n\ts_barrier" ::: "memory");
}

__global__ __launch_bounds__(1024, 4)
void cv_mfma(const float* __restrict__ prv, const float* __restrict__ nxt,
             float* __restrict__ out) {
    __shared__ short4_t sm[2][BSLOTS];   // 147.7 KB total

    const int tid = threadIdx.x;
    const int w0 = blockIdx.x * WT;
    const int h0 = blockIdx.y * HT;
    const int b  = blockIdx.z;

    const int lane = tid & 63;
    const int wid  = tid >> 6;      // 0..15: wave owns output row h0+wid
    const int lq = lane & 15;
    const int lc = lane >> 4;

    const int tp  = tid >> 4;       // 0..63: B pixel sub-index for staging
    const int c16 = tid & 15;       // 0..15: 4-channel granule within phase

    // ---- B staging offsets (phase adds it*KS); 1024 thr x 9 slots = 9216 = 576*16 exact
    int boff[NSB];
    unsigned bmask = 0;
#pragma unroll
    for (int i = 0; i < NSB; ++i) {
        const int p = tp + 64 * i;        // 0..575
        const int row = p / BCOLS;
        const int col = p - row * BCOLS;
        const int gh = h0 - 4 + row;
        const int gw = w0 - 4 + col;
        const bool inb = ((unsigned)gh < (unsigned)H_) && ((unsigned)gw < (unsigned)W_);
        if (inb) bmask |= (1u << i);
        boff[i] = ((b * H_ + (inb ? gh : 0)) * W_ + (inb ? gw : 0)) * C_ + c16 * 4;
    }

    // ---- A: wave-private row; thread covers pixel (wid, lq), ch lc*8 (+32 per ksub)
    const int aoff = ((b * H_ + h0 + wid) * W_ + w0 + lq) * C_ + lc * 8;

    // ---- prologue: stage B(0) into sm[0]; load A(0)
    float4 xa[4];   // phase-cur A data: ksub0 {0,4}, ksub1 {32,36}
    xa[0] = *(const float4*)(prv + aoff);
    xa[1] = *(const float4*)(prv + aoff + 4);
    xa[2] = *(const float4*)(prv + aoff + 32);
    xa[3] = *(const float4*)(prv + aoff + 36);
    {
        float4 v[NSB];
#pragma unroll
        for (int i = 0; i < NSB; ++i) {
            v[i] = make_float4(0.f, 0.f, 0.f, 0.f);
            if (bmask & (1u << i)) v[i] = *(const float4*)(nxt + boff[i]);
        }
#pragma unroll
        for (int i = 0; i < NSB; ++i)
            sm[0][c16 * BSTR + tp + 64 * i] = cvt4(v[i]);
    }

    f32x4 acc[ND][2];
#pragma unroll
    for (int d = 0; d < ND; ++d) {
        acc[d][0] = (f32x4){0.f, 0.f, 0.f, 0.f};
        acc[d][1] = (f32x4){0.f, 0.f, 0.f, 0.f};
    }

    barrier_lgkm();   // B(0) visible

    for (int it = 0; it < NK; ++it) {
        short4_t* sBc = sm[it & 1];          // read buffer (this phase)
        short4_t* sBn = sm[(it + 1) & 1];    // write buffer (free: all waves passed
                                             // the barrier => done with compute(it-1))
        // A frags for this phase (f32 regs die here)
        const short8 af0 = cat(cvt4(xa[0]), cvt4(xa[1]));   // ksub 0: ch it*64+8lc..
        const short8 af1 = cat(cvt4(xa[2]), cvt4(xa[3]));   // ksub 1: +32

        const bool more = (it + 1 < NK);
        const int co = (it + 1) * KS;

        // ---- issue B(it+1) batch 1
        float4 v1[NB1];
#pragma unroll
        for (int i = 0; i < NB1; ++i) {
            v1[i] = make_float4(0.f, 0.f, 0.f, 0.f);
            if (more && (bmask & (1u << i))) v1[i] = *(const float4*)(nxt + boff[i] + co);
        }

        // ---- compute dy 0..4 (batch-1 latency hides under this)
#pragma unroll
        for (int dy = 0; dy < 5; ++dy) {
            const int pB = (wid + dy) * BCOLS + lq;
            const short8 b00 = cat(sBc[(2 * lc) * BSTR + pB],     sBc[(2 * lc + 1) * BSTR + pB]);
            const short8 b01 = cat(sBc[(2 * lc) * BSTR + pB + 8], sBc[(2 * lc + 1) * BSTR + pB + 8]);
            acc[dy][0] = __builtin_amdgcn_mfma_f32_16x16x32_bf16(af0, b00, acc[dy][0], 0, 0, 0);
            acc[dy][1] = __builtin_amdgcn_mfma_f32_16x16x32_bf16(af0, b01, acc[dy][1], 0, 0, 0);
            const short8 b10 = cat(sBc[(8 + 2 * lc) * BSTR + pB],     sBc[(9 + 2 * lc) * BSTR + pB]);
            const short8 b11 = cat(sBc[(8 + 2 * lc) * BSTR + pB + 8], sBc[(9 + 2 * lc) * BSTR + pB + 8]);
            acc[dy][0] = __builtin_amdgcn_mfma_f32_16x16x32_bf16(af1, b10, acc[dy][0], 0, 0, 0);
            acc[dy][1] = __builtin_amdgcn_mfma_f32_16x16x32_bf16(af1, b11, acc[dy][1], 0, 0, 0);
        }

        // ---- write batch 1 to the free buffer; issue batch 2
        if (more) {
#pragma unroll
            for (int i = 0; i < NB1; ++i)
                sBn[c16 * BSTR + tp + 64 * i] = cvt4(v1[i]);
        }
        float4 v2[NB2];
#pragma unroll
        for (int i = 0; i < NB2; ++i) {
            v2[i] = make_float4(0.f, 0.f, 0.f, 0.f);
            if (more && (bmask & (1u << (NB1 + i)))) v2[i] = *(const float4*)(nxt + boff[NB1 + i] + co);
        }

        // ---- compute dy 5..8 (batch-2 latency hides under this)
#pragma unroll
        for (int dy = 5; dy < ND; ++dy) {
            const int pB = (wid + dy) * BCOLS + lq;
            const short8 b00 = cat(sBc[(2 * lc) * BSTR + pB],     sBc[(2 * lc + 1) * BSTR + pB]);
            const short8 b01 = cat(sBc[(2 * lc) * BSTR + pB + 8], sBc[(2 * lc + 1) * BSTR + pB + 8]);
            acc[dy][0] = __builtin_amdgcn_mfma_f32_16x16x32_bf16(af0, b00, acc[dy][0], 0, 0, 0);
            acc[dy][1] = __builtin_amdgcn_mfma_f32_16x16x32_bf16(af0, b01, acc[dy][1], 0, 0, 0);
            const short8 b10 = cat(sBc[(8 + 2 * lc) * BSTR + pB],     sBc[(9 + 2 * lc) * BSTR + pB]);
            const short8 b11 = cat(sBc[(8 + 2 * lc) * BSTR + pB + 8], sBc[(9 + 2 * lc) * BSTR + pB + 8]);
            acc[dy][0] = __builtin_amdgcn_mfma_f32_16x16x32_bf16(af1, b10, acc[dy][0], 0, 0, 0);
            acc[dy][1] = __builtin_amdgcn_mfma_f32_16x16x32_bf16(af1, b11, acc[dy][1], 0, 0, 0);
        }

        // ---- write batch 2; issue A(it+1)
        if (more) {
#pragma unroll
            for (int i = 0; i < NB2; ++i)
                sBn[c16 * BSTR + tp + 64 * (NB1 + i)] = cvt4(v2[i]);
            xa[0] = *(const float4*)(prv + aoff + co);
            xa[1] = *(const float4*)(prv + aoff + co + 4);
            xa[2] = *(const float4*)(prv + aoff + co + 32);
            xa[3] = *(const float4*)(prv + aoff + co + 36);
        }

        barrier_lgkm();   // B(it+1) visible; global loads not drained
    }

    // ---- epilogue (R5/R12/R13-verified): D col=lane&15 (q), D row=4*lc+rg (rD=w-pos).
    // rows rD<8 from tile0 (dx=q-rD), rD>=8 from tile1 (dx=q-rD+8); exclusive+complete.
    const float inv = 1.0f / (float)C_;
    const int h = h0 + wid;
    if (lc < 2) {
#pragma unroll
        for (int rg = 0; rg < 4; ++rg) {
            const int r = 4 * lc + rg;
            const int dx = lq - r;
            if (dx >= 0 && dx <= 8) {
                float* o = out + (size_t)((b * H_ + h) * W_ + w0 + r) * NDISP + dx;
#pragma unroll
                for (int dy = 0; dy < ND; ++dy) {
                    const float v = acc[dy][0][rg] * inv;
                    o[dy * ND] = v >= 0.f ? v : 0.1f * v;
                }
            }
        }
    } else {
#pragma unroll
        for (int rg = 0; rg < 4; ++rg) {
            const int r = 4 * lc + rg;       // 8..15
            const int dx = lq - r + 8;
            if (dx >= 0 && dx <= 8) {
                float* o = out + (size_t)((b * H_ + h) * W_ + w0 + r) * NDISP + dx;
#pragma unroll
                for (int dy = 0; dy < ND; ++dy) {
                    const float v = acc[dy][1][rg] * inv;
                    o[dy * ND] = v >= 0.f ? v : 0.1f * v;
                }
            }
        }
    }
}

extern "C" void kernel_launch(void* const* d_in, const int* in_sizes, int n_in,
                              void* d_out, int out_size, void* d_ws, size_t ws_size,
                              hipStream_t stream) {
    const float* prv = (const float*)d_in[0];
    const float* nxt = (const float*)d_in[1];
    float* out = (float*)d_out;

    dim3 grid(W_ / WT, H_ / HT, B_);   // (8, 8, 8) = 512 blocks x 1024 threads
    cv_mfma<<<grid, 1024, 0, stream>>>(prv, nxt, out);
}